// Round 1
// baseline (259.689 us; speedup 1.0000x reference)
//
#include <hip/hip_runtime.h>

#define CIN   512
#define COUT  256
#define HWDIM 32
#define NBATCH 64
#define PIX_PER_IMG (HWDIM * HWDIM)          // 1024
#define NPIX (NBATCH * PIX_PER_IMG)          // 65536

typedef __attribute__((ext_vector_type(4))) int i32x4;

// ---------------- workspace layout ----------------
// xb8   : [64*32][32][512] int8 signs (NHWC)           33,554,432 B @ 0
// wb8   : [9][256][512]    int8 signs                   1,179,648 B @ 33,554,432
// conv  : [64][256][1024]  int16                       33,554,432 B @ 34,734,080
// sum   : 256 int32                                         1,024 B @ 68,288,512
// sumsq : 256 uint64                                        2,048 B @ 68,289,536
// scale : 256 f32                                           1,024 B @ 68,291,584
// shift : 256 f32                                           1,024 B @ 68,292,608
// zero  : 256 B zero page                                     256 B @ 68,293,632
#define OFF_XB    ((size_t)0)
#define OFF_WB    ((size_t)33554432)
#define OFF_CONV  ((size_t)34734080)
#define OFF_STATS ((size_t)68288512)
#define OFF_SCALE ((size_t)68291584)
#define OFF_SHIFT ((size_t)68292608)
#define OFF_ZERO  ((size_t)68293632)

// ---------------- pack x: f32 NCHW -> int8 sign NHWC ----------------
__global__ __launch_bounds__(256) void pack_x_kernel(const float* __restrict__ x,
                                                     signed char* __restrict__ xb) {
  const int plane = blockIdx.x;            // n*32 + h, 2048 planes
  const int n = plane >> 5, h = plane & 31;
  __shared__ signed char tile[CIN * HWDIM];   // [ci][w], 16 KB
  const int t = threadIdx.x;
  const float* xp = x + (size_t)n * CIN * PIX_PER_IMG + (size_t)h * HWDIM;
#pragma unroll
  for (int it = 0; it < 16; ++it) {
    int e = (it * 256 + t) * 4;            // element in [ci][w] plane
    int ci = e >> 5, w = e & 31;
    float4 v = *reinterpret_cast<const float4*>(xp + (size_t)ci * PIX_PER_IMG + w);
    signed char* tp = &tile[ci * HWDIM + w];
    tp[0] = v.x >= 0.f ? 1 : -1;
    tp[1] = v.y >= 0.f ? 1 : -1;
    tp[2] = v.z >= 0.f ? 1 : -1;
    tp[3] = v.w >= 0.f ? 1 : -1;
  }
  __syncthreads();
  signed char* op = xb + (size_t)plane * (HWDIM * CIN);
#pragma unroll
  for (int it = 0; it < 4; ++it) {
    int cc = it * 256 + t;                 // 16B chunk id, 0..1023
    int w = cc >> 5, ci0 = (cc & 31) << 4;
    union { signed char b[16]; int4 v; } u;
#pragma unroll
    for (int j = 0; j < 16; ++j) u.b[j] = tile[(ci0 + j) * HWDIM + w];
    *reinterpret_cast<int4*>(op + (size_t)w * CIN + ci0) = u.v;
  }
}

// ---------------- pack W: f32 OIHW -> int8 sign [tap][co][ci] ----------------
__global__ __launch_bounds__(256) void pack_w_kernel(const float* __restrict__ W,
                                                     signed char* __restrict__ wb) {
  int idx = blockIdx.x * 256 + threadIdx.x;     // 9*256*512 total
  int tap = idx / (COUT * CIN);
  int rem = idx - tap * (COUT * CIN);
  int co = rem >> 9;
  int ci = rem & 511;
  float v = W[((size_t)co * CIN + ci) * 9 + tap];
  wb[idx] = v >= 0.f ? 1 : -1;
}

// ---------------- conv: i8 MFMA GEMM over 9 taps ----------------
#define BM 128
#define BK 64
#define ASZ (BM * BK)       // 8192
#define BSZ (BK * COUT)     // 16384

__device__ __forceinline__ void load16(const void* g, void* l) {
  __builtin_amdgcn_global_load_lds((const __attribute__((address_space(1))) void*)g,
                                   (__attribute__((address_space(3))) void*)l, 16, 0, 0);
}

__global__ __launch_bounds__(512, 1) void conv_kernel(
    const signed char* __restrict__ xb,    // [2048][32][512]
    const signed char* __restrict__ wb,    // [9][256][512]
    short* __restrict__ cv,                // [64][256][1024]
    const signed char* __restrict__ zp) {
  __shared__ signed char lds[2][ASZ + BSZ];  // 49152 B
  const int t = threadIdx.x;
  const int wid = t >> 6, lane = t & 63;
  const int b = blockIdx.x;                  // 0..511
  const int R0 = b * 4;                      // global image-row base (n*32+h)

  // A-staging geometry (per-thread, fixed except tap shift)
  const int apix = t >> 2;                   // 0..127
  const int acoff = (t & 3) << 4;            // 0,16,32,48
  const int ar = apix >> 5;                  // local row 0..3
  const int aw = apix & 31;                  // w
  const int aR = R0 + ar;
  const int ah = aR & 31;                    // h
  const int an = aR >> 5;                    // n

  const int wr = wid >> 2;                   // 0..1   (M dir)
  const int wc = wid & 3;                    // 0..3   (N dir)

  i32x4 acc[4][4];
#pragma unroll
  for (int m = 0; m < 4; ++m)
#pragma unroll
    for (int n = 0; n < 4; ++n) { i32x4 z = {0, 0, 0, 0}; acc[m][n] = z; }

  auto stage = [&](int buf, int step) {
    const int tap = step >> 3;
    const int s   = step & 7;
    const int ci0 = s << 6;
    const int dh = tap / 3 - 1, dw = tap % 3 - 1;
    // A tile: [128 pixels][64 ci] = 8192 B, 512 threads x 16 B
    {
      int hs = ah + dh, ws = aw + dw;
      bool ok = ((unsigned)hs < 32u) && ((unsigned)ws < 32u);
      const signed char* src = ok
          ? xb + (((size_t)(an * 32 + hs) * 32 + ws) * CIN + ci0 + acoff)
          : zp + acoff;
      load16(src, (void*)&lds[buf][wid * 1024]);
    }
    // B tile: [256 co][64 ci] = 16384 B, 512 threads x 2 x 16 B
#pragma unroll
    for (int it = 0; it < 2; ++it) {
      int c = it * 512 + t;                  // 16B chunk id
      int co = c >> 2, cioff = (c & 3) << 4;
      const signed char* src = wb + ((size_t)tap * COUT + co) * CIN + ci0 + cioff;
      load16(src, (void*)&lds[buf][ASZ + (it * 8 + wid) * 1024]);
    }
  };

  stage(0, 0);
  __syncthreads();

  int cur = 0;
  const int koff = (lane >> 4) << 4;         // 0,16,32,48 (bytes = i8 k-offset)
  for (int step = 0; step < 72; ++step) {
    if (step + 1 < 72) stage(cur ^ 1, step + 1);
    const signed char* Ab = &lds[cur][0];
    const signed char* Bb = &lds[cur][ASZ];
    i32x4 af[4], bf[4];
#pragma unroll
    for (int m = 0; m < 4; ++m) {
      int row = wr * 64 + m * 16 + (lane & 15);
      af[m] = *reinterpret_cast<const i32x4*>(Ab + row * BK + koff);
    }
#pragma unroll
    for (int n = 0; n < 4; ++n) {
      int col = wc * 64 + n * 16 + (lane & 15);
      bf[n] = *reinterpret_cast<const i32x4*>(Bb + col * BK + koff);
    }
#pragma unroll
    for (int m = 0; m < 4; ++m)
#pragma unroll
      for (int n = 0; n < 4; ++n)
        acc[m][n] = __builtin_amdgcn_mfma_i32_16x16x64_i8(af[m], bf[n], acc[m][n], 0, 0, 0);
    __syncthreads();
    cur ^= 1;
  }

  // epilogue: write int16 conv output, NCHW
  const int P0 = b * BM;
#pragma unroll
  for (int m = 0; m < 4; ++m) {
#pragma unroll
    for (int n = 0; n < 4; ++n) {
      int row = wr * 64 + m * 16 + ((lane >> 4) << 2);   // + reg (0..3) pixels
      int co = wc * 64 + n * 16 + (lane & 15);
      int P = P0 + row;
      int nimg = P >> 10;
      int hw = P & 1023;
      short4 v = make_short4((short)acc[m][n][0], (short)acc[m][n][1],
                             (short)acc[m][n][2], (short)acc[m][n][3]);
      *reinterpret_cast<short4*>(cv + (((size_t)nimg * COUT + co) << 10) + hw) = v;
    }
  }
}

// ---------------- per-channel sum / sumsq ----------------
__global__ __launch_bounds__(256) void reduce_kernel(const short* __restrict__ cv,
                                                     int* __restrict__ sum,
                                                     unsigned long long* __restrict__ sumsq) {
  const int n = blockIdx.x >> 8, co = blockIdx.x & 255;
  const short* p = cv + (((size_t)n * COUT + co) << 10);
  const int t = threadIdx.x;
  short4 v = *reinterpret_cast<const short4*>(p + t * 4);
  int s1 = (int)v.x + v.y + v.z + v.w;
  long long s2 = (long long)((int)v.x * v.x + (int)v.y * v.y +
                             (int)v.z * v.z + (int)v.w * v.w);
#pragma unroll
  for (int off = 32; off > 0; off >>= 1) {
    s1 += __shfl_down(s1, off, 64);
    s2 += __shfl_down(s2, off, 64);
  }
  if ((t & 63) == 0) {
    atomicAdd(&sum[co], s1);
    atomicAdd(&sumsq[co], (unsigned long long)s2);
  }
}

// ---------------- stats -> scale/shift ----------------
__global__ void stats_kernel(const int* __restrict__ sum,
                             const unsigned long long* __restrict__ sumsq,
                             const float* __restrict__ gamma,
                             const float* __restrict__ beta,
                             float* __restrict__ scale,
                             float* __restrict__ shift) {
  int co = threadIdx.x;
  double cnt = (double)NPIX;
  double mean = (double)sum[co] / cnt;
  double ex2 = (double)(long long)sumsq[co] / cnt;
  double var = ex2 - mean * mean;
  double rs = 1.0 / sqrt(var + 1e-5);
  float g = gamma[co];
  scale[co] = (float)rs * g;
  shift[co] = beta[co] - (float)(mean * rs) * g;
}

// ---------------- normalize + residual + clip ----------------
__global__ __launch_bounds__(256) void final_kernel(const short* __restrict__ cv,
                                                    const float* __restrict__ x,
                                                    const float* __restrict__ scale,
                                                    const float* __restrict__ shift,
                                                    float* __restrict__ out) {
  size_t i = ((size_t)blockIdx.x * 256 + threadIdx.x) * 4;
  int co = (int)((i >> 10) & 255);
  size_t n = i >> 18;
  size_t hw = i & 1023;
  short4 c4 = *reinterpret_cast<const short4*>(cv + i);
  float4 r4 = *reinterpret_cast<const float4*>(x + ((n * CIN + co) << 10) + hw);
  float sc = scale[co], sh = shift[co];
  float4 o;
  o.x = fminf(1.f, fmaxf(-1.f, (float)c4.x * sc + sh + r4.x));
  o.y = fminf(1.f, fmaxf(-1.f, (float)c4.y * sc + sh + r4.y));
  o.z = fminf(1.f, fmaxf(-1.f, (float)c4.z * sc + sh + r4.z));
  o.w = fminf(1.f, fmaxf(-1.f, (float)c4.w * sc + sh + r4.w));
  *reinterpret_cast<float4*>(out + i) = o;
}

extern "C" void kernel_launch(void* const* d_in, const int* in_sizes, int n_in,
                              void* d_out, int out_size, void* d_ws, size_t ws_size,
                              hipStream_t stream) {
  const float* x     = (const float*)d_in[0];
  const float* W     = (const float*)d_in[1];
  const float* gamma = (const float*)d_in[2];
  const float* beta  = (const float*)d_in[3];
  float* out = (float*)d_out;
  char* ws = (char*)d_ws;

  signed char* xb = (signed char*)(ws + OFF_XB);
  signed char* wb = (signed char*)(ws + OFF_WB);
  short* cv = (short*)(ws + OFF_CONV);
  int* sum = (int*)(ws + OFF_STATS);
  unsigned long long* sumsq = (unsigned long long*)(ws + OFF_STATS + 1024);
  float* scale = (float*)(ws + OFF_SCALE);
  float* shift = (float*)(ws + OFF_SHIFT);
  signed char* zp = (signed char*)(ws + OFF_ZERO);

  // zero stats accumulators + zero page (deterministic per call)
  hipMemsetAsync(ws + OFF_STATS, 0, 5376, stream);

  pack_x_kernel<<<NBATCH * HWDIM, 256, 0, stream>>>(x, xb);
  pack_w_kernel<<<(9 * COUT * CIN) / 256, 256, 0, stream>>>(W, wb);
  conv_kernel<<<NPIX / BM, 512, 0, stream>>>(xb, wb, cv, zp);
  reduce_kernel<<<NBATCH * COUT, 256, 0, stream>>>(cv, sum, sumsq);
  stats_kernel<<<1, 256, 0, stream>>>(sum, sumsq, gamma, beta, scale, shift);
  final_kernel<<<(NBATCH * COUT * PIX_PER_IMG) / (256 * 4), 256, 0, stream>>>(
      cv, x, scale, shift, out);
}

// Round 2
// 158.457 us; speedup vs baseline: 1.6389x; 1.6389x over previous
//
#include <hip/hip_runtime.h>

#define CIN   512
#define COUT  256
#define HWDIM 32
#define NBATCH 64
#define PIX_PER_IMG (HWDIM * HWDIM)          // 1024
#define NPIX (NBATCH * PIX_PER_IMG)          // 65536

typedef __attribute__((ext_vector_type(4))) int i32x4;

// ---------------- workspace layout ----------------
#define OFF_XB    ((size_t)0)
#define OFF_WB    ((size_t)33554432)
#define OFF_CONV  ((size_t)34734080)
#define OFF_STATS ((size_t)68288512)
#define OFF_SCALE ((size_t)68291584)
#define OFF_SHIFT ((size_t)68292608)
#define OFF_ZERO  ((size_t)68293632)

// ---------------- pack x: f32 NCHW -> int8 sign NHWC ----------------
// Register 4x4 sign-pack + word-granular LDS transpose.
__global__ __launch_bounds__(256) void pack_x_kernel(const float* __restrict__ x,
                                                     signed char* __restrict__ xb) {
  const int plane = blockIdx.x;            // n*32 + h, 2048 planes
  const int n = plane >> 5, h = plane & 31;
  __shared__ int tile[HWDIM * 130];        // [w][130] ints (4 ci-bytes each), 16.25 KB
  const int t = threadIdx.x;
  const float* xp = x + (size_t)n * CIN * PIX_PER_IMG + (size_t)h * HWDIM;
#define SB(v) ((v) >= 0.f ? 0x01u : 0xFFu)
#pragma unroll
  for (int it = 0; it < 4; ++it) {
    int idx = it * 256 + t;                // 0..1023
    int cib = idx >> 3;                    // ci block 0..127 (ci = cib*4)
    int w4 = (idx & 7) << 2;               // 0,4,...,28
    const float* p0 = xp + (size_t)(cib * 4 + 0) * PIX_PER_IMG + w4;
    float4 fa = *reinterpret_cast<const float4*>(p0);
    float4 fb = *reinterpret_cast<const float4*>(p0 + PIX_PER_IMG);
    float4 fc = *reinterpret_cast<const float4*>(p0 + 2 * PIX_PER_IMG);
    float4 fd = *reinterpret_cast<const float4*>(p0 + 3 * PIX_PER_IMG);
    unsigned o0 = SB(fa.x) | (SB(fb.x) << 8) | (SB(fc.x) << 16) | (SB(fd.x) << 24);
    unsigned o1 = SB(fa.y) | (SB(fb.y) << 8) | (SB(fc.y) << 16) | (SB(fd.y) << 24);
    unsigned o2 = SB(fa.z) | (SB(fb.z) << 8) | (SB(fc.z) << 16) | (SB(fd.z) << 24);
    unsigned o3 = SB(fa.w) | (SB(fb.w) << 8) | (SB(fc.w) << 16) | (SB(fd.w) << 24);
    tile[(w4 + 0) * 130 + cib] = (int)o0;
    tile[(w4 + 1) * 130 + cib] = (int)o1;
    tile[(w4 + 2) * 130 + cib] = (int)o2;
    tile[(w4 + 3) * 130 + cib] = (int)o3;
  }
  __syncthreads();
  int2* xo = reinterpret_cast<int2*>(xb + (size_t)plane * (HWDIM * CIN));
#pragma unroll
  for (int it = 0; it < 8; ++it) {
    int cc = it * 256 + t;                 // 8B chunk id 0..2047
    int w = cc >> 6, c8 = cc & 63;
    int2 v = make_int2(tile[w * 130 + c8 * 2], tile[w * 130 + c8 * 2 + 1]);
    xo[cc] = v;                            // = xb[plane][w][c8*8..+7]
  }
}

// ---------------- pack W: f32 OIHW -> int8 sign [tap][co][ci] ----------------
__global__ __launch_bounds__(256) void pack_w_kernel(const float* __restrict__ W,
                                                     signed char* __restrict__ wb) {
  int idx = blockIdx.x * 256 + threadIdx.x;     // 9*256*512 total
  int tap = idx / (COUT * CIN);
  int rem = idx - tap * (COUT * CIN);
  int co = rem >> 9;
  int ci = rem & 511;
  float v = W[((size_t)co * CIN + ci) * 9 + tap];
  wb[idx] = v >= 0.f ? 1 : -1;
}

// ---------------- conv: i8 MFMA GEMM over 9 taps + fused BN reduction ----------------
#define BM 128
#define BK 64
#define ASZ (BM * BK)       // 8192
#define BSZ (BK * COUT)     // 16384

__device__ __forceinline__ void load16(const void* g, void* l) {
  __builtin_amdgcn_global_load_lds((const __attribute__((address_space(1))) void*)g,
                                   (__attribute__((address_space(3))) void*)l, 16, 0, 0);
}

__global__ __launch_bounds__(512, 1) void conv_kernel(
    const signed char* __restrict__ xb,    // [2048][32][512]
    const signed char* __restrict__ wb,    // [9][256][512]
    short* __restrict__ cv,                // [64][256][1024]
    const signed char* __restrict__ zp,
    int* __restrict__ sum,
    unsigned long long* __restrict__ sumsq) {
  __shared__ signed char lds[2][ASZ + BSZ];  // 49152 B
  const int t = threadIdx.x;
  const int wid = t >> 6, lane = t & 63;
  const int b = blockIdx.x;                  // 0..511
  const int R0 = b * 4;                      // global image-row base (n*32+h)

  const int apix = t >> 2;                   // 0..127
  const int acoff = (t & 3) << 4;            // 0,16,32,48
  const int ar = apix >> 5;                  // local row 0..3
  const int aw = apix & 31;                  // w
  const int aR = R0 + ar;
  const int ah = aR & 31;                    // h
  const int an = aR >> 5;                    // n

  const int wr = wid >> 2;                   // 0..1   (M dir)
  const int wc = wid & 3;                    // 0..3   (N dir)

  i32x4 acc[4][4];
#pragma unroll
  for (int m = 0; m < 4; ++m)
#pragma unroll
    for (int n = 0; n < 4; ++n) { i32x4 z = {0, 0, 0, 0}; acc[m][n] = z; }

  auto stage = [&](int buf, int step) {
    const int tap = step >> 3;
    const int s   = step & 7;
    const int ci0 = s << 6;
    const int dh = tap / 3 - 1, dw = tap % 3 - 1;
    {
      int hs = ah + dh, ws = aw + dw;
      bool ok = ((unsigned)hs < 32u) && ((unsigned)ws < 32u);
      const signed char* src = ok
          ? xb + (((size_t)(an * 32 + hs) * 32 + ws) * CIN + ci0 + acoff)
          : zp + acoff;
      load16(src, (void*)&lds[buf][wid * 1024]);
    }
#pragma unroll
    for (int it = 0; it < 2; ++it) {
      int c = it * 512 + t;
      int co = c >> 2, cioff = (c & 3) << 4;
      const signed char* src = wb + ((size_t)tap * COUT + co) * CIN + ci0 + cioff;
      load16(src, (void*)&lds[buf][ASZ + (it * 8 + wid) * 1024]);
    }
  };

  stage(0, 0);
  __syncthreads();

  int cur = 0;
  const int koff = (lane >> 4) << 4;
  for (int step = 0; step < 72; ++step) {
    if (step + 1 < 72) stage(cur ^ 1, step + 1);
    const signed char* Ab = &lds[cur][0];
    const signed char* Bb = &lds[cur][ASZ];
    i32x4 af[4], bf[4];
#pragma unroll
    for (int m = 0; m < 4; ++m) {
      int row = wr * 64 + m * 16 + (lane & 15);
      af[m] = *reinterpret_cast<const i32x4*>(Ab + row * BK + koff);
    }
#pragma unroll
    for (int n = 0; n < 4; ++n) {
      int col = wc * 64 + n * 16 + (lane & 15);
      bf[n] = *reinterpret_cast<const i32x4*>(Bb + col * BK + koff);
    }
#pragma unroll
    for (int m = 0; m < 4; ++m)
#pragma unroll
      for (int n = 0; n < 4; ++n)
        acc[m][n] = __builtin_amdgcn_mfma_i32_16x16x64_i8(af[m], bf[n], acc[m][n], 0, 0, 0);
    __syncthreads();
    cur ^= 1;
  }

  // epilogue A: write int16 conv output, NCHW
  const int P0 = b * BM;
#pragma unroll
  for (int m = 0; m < 4; ++m) {
#pragma unroll
    for (int n = 0; n < 4; ++n) {
      int row = wr * 64 + m * 16 + ((lane >> 4) << 2);
      int co = wc * 64 + n * 16 + (lane & 15);
      int P = P0 + row;
      int nimg = P >> 10;
      int hw = P & 1023;
      short4 v = make_short4((short)acc[m][n][0], (short)acc[m][n][1],
                             (short)acc[m][n][2], (short)acc[m][n][3]);
      *reinterpret_cast<short4*>(cv + (((size_t)nimg * COUT + co) << 10) + hw) = v;
    }
  }

  // epilogue B: fused per-channel sum / sumsq (exact integers)
#pragma unroll
  for (int n = 0; n < 4; ++n) {
    int s1 = 0;
    long long s2 = 0;
#pragma unroll
    for (int m = 0; m < 4; ++m)
#pragma unroll
      for (int j = 0; j < 4; ++j) {
        int v = acc[m][n][j];
        s1 += v;
        s2 += (long long)v * v;
      }
    s1 += __shfl_xor(s1, 16, 64);
    s1 += __shfl_xor(s1, 32, 64);
    s2 += __shfl_xor(s2, 16, 64);
    s2 += __shfl_xor(s2, 32, 64);
    if (lane < 16) {
      int c = wc * 64 + n * 16 + lane;
      atomicAdd(&sum[c], s1);
      atomicAdd(&sumsq[c], (unsigned long long)s2);
    }
  }
}

// ---------------- stats -> scale/shift ----------------
__global__ void stats_kernel(const int* __restrict__ sum,
                             const unsigned long long* __restrict__ sumsq,
                             const float* __restrict__ gamma,
                             const float* __restrict__ beta,
                             float* __restrict__ scale,
                             float* __restrict__ shift) {
  int co = threadIdx.x;
  double cnt = (double)NPIX;
  double mean = (double)sum[co] / cnt;
  double ex2 = (double)(long long)sumsq[co] / cnt;
  double var = ex2 - mean * mean;
  double rs = 1.0 / sqrt(var + 1e-5);
  float g = gamma[co];
  scale[co] = (float)rs * g;
  shift[co] = beta[co] - (float)(mean * rs) * g;
}

// ---------------- normalize + residual + clip (8 elems/thread) ----------------
__global__ __launch_bounds__(256) void final_kernel(const short* __restrict__ cv,
                                                    const float* __restrict__ x,
                                                    const float* __restrict__ scale,
                                                    const float* __restrict__ shift,
                                                    float* __restrict__ out) {
  size_t i = ((size_t)blockIdx.x * 256 + threadIdx.x) * 8;
  int co = (int)((i >> 10) & 255);
  size_t n = i >> 18;
  size_t hw = i & 1023;
  short4 c0 = *reinterpret_cast<const short4*>(cv + i);
  short4 c1 = *reinterpret_cast<const short4*>(cv + i + 4);
  const float* xr = x + ((n * CIN + co) << 10) + hw;
  float4 r0 = *reinterpret_cast<const float4*>(xr);
  float4 r1 = *reinterpret_cast<const float4*>(xr + 4);
  float sc = scale[co], sh = shift[co];
  float4 o0, o1;
  o0.x = fminf(1.f, fmaxf(-1.f, (float)c0.x * sc + sh + r0.x));
  o0.y = fminf(1.f, fmaxf(-1.f, (float)c0.y * sc + sh + r0.y));
  o0.z = fminf(1.f, fmaxf(-1.f, (float)c0.z * sc + sh + r0.z));
  o0.w = fminf(1.f, fmaxf(-1.f, (float)c0.w * sc + sh + r0.w));
  o1.x = fminf(1.f, fmaxf(-1.f, (float)c1.x * sc + sh + r1.x));
  o1.y = fminf(1.f, fmaxf(-1.f, (float)c1.y * sc + sh + r1.y));
  o1.z = fminf(1.f, fmaxf(-1.f, (float)c1.z * sc + sh + r1.z));
  o1.w = fminf(1.f, fmaxf(-1.f, (float)c1.w * sc + sh + r1.w));
  *reinterpret_cast<float4*>(out + i) = o0;
  *reinterpret_cast<float4*>(out + i + 4) = o1;
}

extern "C" void kernel_launch(void* const* d_in, const int* in_sizes, int n_in,
                              void* d_out, int out_size, void* d_ws, size_t ws_size,
                              hipStream_t stream) {
  const float* x     = (const float*)d_in[0];
  const float* W     = (const float*)d_in[1];
  const float* gamma = (const float*)d_in[2];
  const float* beta  = (const float*)d_in[3];
  float* out = (float*)d_out;
  char* ws = (char*)d_ws;

  signed char* xb = (signed char*)(ws + OFF_XB);
  signed char* wb = (signed char*)(ws + OFF_WB);
  short* cv = (short*)(ws + OFF_CONV);
  int* sum = (int*)(ws + OFF_STATS);
  unsigned long long* sumsq = (unsigned long long*)(ws + OFF_STATS + 1024);
  float* scale = (float*)(ws + OFF_SCALE);
  float* shift = (float*)(ws + OFF_SHIFT);
  signed char* zp = (signed char*)(ws + OFF_ZERO);

  hipMemsetAsync(ws + OFF_STATS, 0, 5376, stream);

  pack_x_kernel<<<NBATCH * HWDIM, 256, 0, stream>>>(x, xb);
  pack_w_kernel<<<(9 * COUT * CIN) / 256, 256, 0, stream>>>(W, wb);
  conv_kernel<<<NPIX / BM, 512, 0, stream>>>(xb, wb, cv, zp, sum, sumsq);
  stats_kernel<<<1, 256, 0, stream>>>(sum, sumsq, gamma, beta, scale, shift);
  final_kernel<<<(NBATCH * COUT * PIX_PER_IMG) / (256 * 8), 256, 0, stream>>>(
      cv, x, scale, shift, out);
}

// Round 3
// 155.677 us; speedup vs baseline: 1.6681x; 1.0179x over previous
//
#include <hip/hip_runtime.h>

#define CIN   512
#define COUT  256
#define HWDIM 32
#define NBATCH 64
#define PIX_PER_IMG (HWDIM * HWDIM)          // 1024
#define NPIX (NBATCH * PIX_PER_IMG)          // 65536

typedef __attribute__((ext_vector_type(4))) int i32x4;

// ---------------- workspace layout ----------------
#define OFF_XB    ((size_t)0)
#define OFF_WB    ((size_t)33554432)
#define OFF_CONV  ((size_t)34734080)
#define OFF_STATS ((size_t)68288512)
#define OFF_SCALE ((size_t)68291584)
#define OFF_SHIFT ((size_t)68292608)
#define OFF_ZERO  ((size_t)68293632)

// ---------------- pack x: f32 NCHW -> int8 sign NHWC ----------------
__global__ __launch_bounds__(256) void pack_x_kernel(const float* __restrict__ x,
                                                     signed char* __restrict__ xb) {
  const int plane = blockIdx.x;            // n*32 + h, 2048 planes
  const int n = plane >> 5, h = plane & 31;
  __shared__ int tile[HWDIM * 130];        // [w][130] ints (4 ci-bytes each)
  const int t = threadIdx.x;
  const float* xp = x + (size_t)n * CIN * PIX_PER_IMG + (size_t)h * HWDIM;
#define SB(v) ((v) >= 0.f ? 0x01u : 0xFFu)
#pragma unroll
  for (int it = 0; it < 4; ++it) {
    int idx = it * 256 + t;                // 0..1023
    int cib = idx >> 3;                    // ci block 0..127 (ci = cib*4)
    int w4 = (idx & 7) << 2;               // 0,4,...,28
    const float* p0 = xp + (size_t)(cib * 4 + 0) * PIX_PER_IMG + w4;
    float4 fa = *reinterpret_cast<const float4*>(p0);
    float4 fb = *reinterpret_cast<const float4*>(p0 + PIX_PER_IMG);
    float4 fc = *reinterpret_cast<const float4*>(p0 + 2 * PIX_PER_IMG);
    float4 fd = *reinterpret_cast<const float4*>(p0 + 3 * PIX_PER_IMG);
    unsigned o0 = SB(fa.x) | (SB(fb.x) << 8) | (SB(fc.x) << 16) | (SB(fd.x) << 24);
    unsigned o1 = SB(fa.y) | (SB(fb.y) << 8) | (SB(fc.y) << 16) | (SB(fd.y) << 24);
    unsigned o2 = SB(fa.z) | (SB(fb.z) << 8) | (SB(fc.z) << 16) | (SB(fd.z) << 24);
    unsigned o3 = SB(fa.w) | (SB(fb.w) << 8) | (SB(fc.w) << 16) | (SB(fd.w) << 24);
    tile[(w4 + 0) * 130 + cib] = (int)o0;
    tile[(w4 + 1) * 130 + cib] = (int)o1;
    tile[(w4 + 2) * 130 + cib] = (int)o2;
    tile[(w4 + 3) * 130 + cib] = (int)o3;
  }
  __syncthreads();
  int2* xo = reinterpret_cast<int2*>(xb + (size_t)plane * (HWDIM * CIN));
#pragma unroll
  for (int it = 0; it < 8; ++it) {
    int cc = it * 256 + t;                 // 8B chunk id 0..2047
    int w = cc >> 6, c8 = cc & 63;
    int2 v = make_int2(tile[w * 130 + c8 * 2], tile[w * 130 + c8 * 2 + 1]);
    xo[cc] = v;
  }
}

// ---------------- pack W: f32 OIHW -> int8 sign [tap][co][ci] ----------------
__global__ __launch_bounds__(256) void pack_w_kernel(const float* __restrict__ W,
                                                     signed char* __restrict__ wb) {
  int idx = blockIdx.x * 256 + threadIdx.x;     // 9*256*512 total
  int tap = idx / (COUT * CIN);
  int rem = idx - tap * (COUT * CIN);
  int co = rem >> 9;
  int ci = rem & 511;
  float v = W[((size_t)co * CIN + ci) * 9 + tap];
  wb[idx] = v >= 0.f ? 1 : -1;
}

// ---------------- conv: i8 MFMA GEMM over 9 taps + fused BN reduction ----------------
#define BM 128
#define BK 64
#define ASZ (BM * BK)       // 8192
#define BSZ (BK * COUT)     // 16384

__device__ __forceinline__ void load16(const void* g, void* l) {
  __builtin_amdgcn_global_load_lds((const __attribute__((address_space(1))) void*)g,
                                   (__attribute__((address_space(3))) void*)l, 16, 0, 0);
}

__global__ __launch_bounds__(512, 1) void conv_kernel(
    const signed char* __restrict__ xb,    // [2048][32][512]
    const signed char* __restrict__ wb,    // [9][256][512]
    short* __restrict__ cv,                // [64][256][1024]
    const signed char* __restrict__ zp,
    int* __restrict__ sum,
    unsigned long long* __restrict__ sumsq) {
  __shared__ signed char lds[2][ASZ + BSZ];  // 49152 B
  const int t = threadIdx.x;
  const int wid = t >> 6, lane = t & 63;
  const int b = blockIdx.x;                  // 0..511
  const int R0 = b * 4;                      // global image-row base (n*32+h)

  // staging geometry: dest chunk index == t (A) / c (B); row = idx>>2, slot = idx&3.
  // T2 swizzle: linear LDS dest + source slot ^= (row>>1)&3 (rule 21).
  const int apix = t >> 2;                   // A row 0..127
  const int acoff = (((t & 3) ^ ((t >> 3) & 3)) << 4);   // swizzled source ci-offset
  const int ar = apix >> 5;                  // local row 0..3
  const int aw = apix & 31;                  // w
  const int aR = R0 + ar;
  const int ah = aR & 31;                    // h
  const int an = aR >> 5;                    // n

  const int wr = wid >> 2;                   // 0..1   (M dir)
  const int wc = wid & 3;                    // 0..3   (N dir)

  i32x4 acc[4][4];
#pragma unroll
  for (int m = 0; m < 4; ++m)
#pragma unroll
    for (int n = 0; n < 4; ++n) { i32x4 z = {0, 0, 0, 0}; acc[m][n] = z; }

  auto stage = [&](int buf, int step) {
    const int tap = step >> 3;
    const int s   = step & 7;
    const int ci0 = s << 6;
    const int dh = tap / 3 - 1, dw = tap % 3 - 1;
    {
      int hs = ah + dh, ws = aw + dw;
      bool ok = ((unsigned)hs < 32u) && ((unsigned)ws < 32u);
      const signed char* src = ok
          ? xb + (((size_t)(an * 32 + hs) * 32 + ws) * CIN + ci0 + acoff)
          : zp + acoff;
      load16(src, (void*)&lds[buf][wid * 1024]);
    }
#pragma unroll
    for (int it = 0; it < 2; ++it) {
      int c = it * 512 + t;
      int co = c >> 2;
      int cioff = (((c & 3) ^ ((c >> 3) & 3)) << 4);     // same swizzle
      const signed char* src = wb + ((size_t)tap * COUT + co) * CIN + ci0 + cioff;
      load16(src, (void*)&lds[buf][ASZ + (it * 8 + wid) * 1024]);
    }
  };

  // read-side swizzled offsets (XOR value uniform in m/n: (row>>1)&3 == ((lane&15)>>1)&3)
  const int koff = (lane >> 4) << 4;
  const int ksw  = ((((lane & 15) >> 1) & 3) << 4);
  int aoff[4], boff[4];
#pragma unroll
  for (int m = 0; m < 4; ++m) {
    int row = wr * 64 + m * 16 + (lane & 15);
    aoff[m] = row * BK + (koff ^ ksw);
  }
#pragma unroll
  for (int n = 0; n < 4; ++n) {
    int col = wc * 64 + n * 16 + (lane & 15);
    boff[n] = ASZ + col * BK + (koff ^ ksw);
  }

  stage(0, 0);
  int cur = 0;
  for (int step = 0; step < 72; ++step) {
    // phase 1: issue next-tile loads; counted vmcnt keeps them in flight (T4)
    if (step + 1 < 72) {
      stage(cur ^ 1, step + 1);
      asm volatile("s_waitcnt vmcnt(3)" ::: "memory");   // oldest 3 (= cur's) done
    } else {
      asm volatile("s_waitcnt vmcnt(0)" ::: "memory");
    }
    __builtin_amdgcn_s_barrier();
    // phase 2: ds_read + MFMA on cur
    const signed char* base = &lds[cur][0];
    i32x4 af[4], bf[4];
#pragma unroll
    for (int m = 0; m < 4; ++m)
      af[m] = *reinterpret_cast<const i32x4*>(base + aoff[m]);
#pragma unroll
    for (int n = 0; n < 4; ++n)
      bf[n] = *reinterpret_cast<const i32x4*>(base + boff[n]);
    __builtin_amdgcn_s_setprio(1);
#pragma unroll
    for (int m = 0; m < 4; ++m)
#pragma unroll
      for (int n = 0; n < 4; ++n)
        acc[m][n] = __builtin_amdgcn_mfma_i32_16x16x64_i8(af[m], bf[n], acc[m][n], 0, 0, 0);
    __builtin_amdgcn_s_setprio(0);
    asm volatile("s_waitcnt lgkmcnt(0)" ::: "memory");   // reads of cur drained
    __builtin_amdgcn_s_barrier();                        // before next iter overwrites cur
    cur ^= 1;
  }

  // epilogue A: write int16 conv output, NCHW
  const int P0 = b * BM;
#pragma unroll
  for (int m = 0; m < 4; ++m) {
#pragma unroll
    for (int n = 0; n < 4; ++n) {
      int row = wr * 64 + m * 16 + ((lane >> 4) << 2);
      int co = wc * 64 + n * 16 + (lane & 15);
      int P = P0 + row;
      int nimg = P >> 10;
      int hw = P & 1023;
      short4 v = make_short4((short)acc[m][n][0], (short)acc[m][n][1],
                             (short)acc[m][n][2], (short)acc[m][n][3]);
      *reinterpret_cast<short4*>(cv + (((size_t)nimg * COUT + co) << 10) + hw) = v;
    }
  }

  // epilogue B: fused per-channel sum / sumsq (exact integers)
#pragma unroll
  for (int n = 0; n < 4; ++n) {
    int s1 = 0;
    long long s2 = 0;
#pragma unroll
    for (int m = 0; m < 4; ++m)
#pragma unroll
      for (int j = 0; j < 4; ++j) {
        int v = acc[m][n][j];
        s1 += v;
        s2 += (long long)v * v;
      }
    s1 += __shfl_xor(s1, 16, 64);
    s1 += __shfl_xor(s1, 32, 64);
    s2 += __shfl_xor(s2, 16, 64);
    s2 += __shfl_xor(s2, 32, 64);
    if (lane < 16) {
      int c = wc * 64 + n * 16 + lane;
      atomicAdd(&sum[c], s1);
      atomicAdd(&sumsq[c], (unsigned long long)s2);
    }
  }
}

// ---------------- stats -> scale/shift ----------------
__global__ void stats_kernel(const int* __restrict__ sum,
                             const unsigned long long* __restrict__ sumsq,
                             const float* __restrict__ gamma,
                             const float* __restrict__ beta,
                             float* __restrict__ scale,
                             float* __restrict__ shift) {
  int co = threadIdx.x;
  double cnt = (double)NPIX;
  double mean = (double)sum[co] / cnt;
  double ex2 = (double)(long long)sumsq[co] / cnt;
  double var = ex2 - mean * mean;
  double rs = 1.0 / sqrt(var + 1e-5);
  float g = gamma[co];
  scale[co] = (float)rs * g;
  shift[co] = beta[co] - (float)(mean * rs) * g;
}

// ---------------- normalize + residual + clip (8 elems/thread) ----------------
__global__ __launch_bounds__(256) void final_kernel(const short* __restrict__ cv,
                                                    const float* __restrict__ x,
                                                    const float* __restrict__ scale,
                                                    const float* __restrict__ shift,
                                                    float* __restrict__ out) {
  size_t i = ((size_t)blockIdx.x * 256 + threadIdx.x) * 8;
  int co = (int)((i >> 10) & 255);
  size_t n = i >> 18;
  size_t hw = i & 1023;
  short4 c0 = *reinterpret_cast<const short4*>(cv + i);
  short4 c1 = *reinterpret_cast<const short4*>(cv + i + 4);
  const float* xr = x + ((n * CIN + co) << 10) + hw;
  float4 r0 = *reinterpret_cast<const float4*>(xr);
  float4 r1 = *reinterpret_cast<const float4*>(xr + 4);
  float sc = scale[co], sh = shift[co];
  float4 o0, o1;
  o0.x = fminf(1.f, fmaxf(-1.f, (float)c0.x * sc + sh + r0.x));
  o0.y = fminf(1.f, fmaxf(-1.f, (float)c0.y * sc + sh + r0.y));
  o0.z = fminf(1.f, fmaxf(-1.f, (float)c0.z * sc + sh + r0.z));
  o0.w = fminf(1.f, fmaxf(-1.f, (float)c0.w * sc + sh + r0.w));
  o1.x = fminf(1.f, fmaxf(-1.f, (float)c1.x * sc + sh + r1.x));
  o1.y = fminf(1.f, fmaxf(-1.f, (float)c1.y * sc + sh + r1.y));
  o1.z = fminf(1.f, fmaxf(-1.f, (float)c1.z * sc + sh + r1.z));
  o1.w = fminf(1.f, fmaxf(-1.f, (float)c1.w * sc + sh + r1.w));
  *reinterpret_cast<float4*>(out + i) = o0;
  *reinterpret_cast<float4*>(out + i + 4) = o1;
}

extern "C" void kernel_launch(void* const* d_in, const int* in_sizes, int n_in,
                              void* d_out, int out_size, void* d_ws, size_t ws_size,
                              hipStream_t stream) {
  const float* x     = (const float*)d_in[0];
  const float* W     = (const float*)d_in[1];
  const float* gamma = (const float*)d_in[2];
  const float* beta  = (const float*)d_in[3];
  float* out = (float*)d_out;
  char* ws = (char*)d_ws;

  signed char* xb = (signed char*)(ws + OFF_XB);
  signed char* wb = (signed char*)(ws + OFF_WB);
  short* cv = (short*)(ws + OFF_CONV);
  int* sum = (int*)(ws + OFF_STATS);
  unsigned long long* sumsq = (unsigned long long*)(ws + OFF_STATS + 1024);
  float* scale = (float*)(ws + OFF_SCALE);
  float* shift = (float*)(ws + OFF_SHIFT);
  signed char* zp = (signed char*)(ws + OFF_ZERO);

  hipMemsetAsync(ws + OFF_STATS, 0, 5376, stream);

  pack_x_kernel<<<NBATCH * HWDIM, 256, 0, stream>>>(x, xb);
  pack_w_kernel<<<(9 * COUT * CIN) / 256, 256, 0, stream>>>(W, wb);
  conv_kernel<<<NPIX / BM, 512, 0, stream>>>(xb, wb, cv, zp, sum, sumsq);
  stats_kernel<<<1, 256, 0, stream>>>(sum, sumsq, gamma, beta, scale, shift);
  final_kernel<<<(NBATCH * COUT * PIX_PER_IMG) / (256 * 8), 256, 0, stream>>>(
      cv, x, scale, shift, out);
}

// Round 4
// 145.952 us; speedup vs baseline: 1.7793x; 1.0666x over previous
//
#include <hip/hip_runtime.h>

#define CIN   512
#define COUT  256
#define HWDIM 32
#define NBATCH 64
#define PIX_PER_IMG (HWDIM * HWDIM)          // 1024
#define NPIX (NBATCH * PIX_PER_IMG)          // 65536

typedef __attribute__((ext_vector_type(4))) int i32x4;

// ---------------- workspace layout ----------------
#define OFF_XB    ((size_t)0)
#define OFF_WB    ((size_t)33554432)
#define OFF_CONV  ((size_t)34734080)
#define OFF_STATS ((size_t)68288512)
#define OFF_SCALE ((size_t)68291584)
#define OFF_SHIFT ((size_t)68292608)
#define OFF_ZERO  ((size_t)68293632)

// ---------------- pack x: f32 NCHW -> int8 sign NHWC ----------------
__global__ __launch_bounds__(256) void pack_x_kernel(const float* __restrict__ x,
                                                     signed char* __restrict__ xb) {
  const int plane = blockIdx.x;            // n*32 + h, 2048 planes
  const int n = plane >> 5, h = plane & 31;
  __shared__ int tile[HWDIM * 130];        // [w][130] ints (4 ci-bytes each)
  const int t = threadIdx.x;
  const float* xp = x + (size_t)n * CIN * PIX_PER_IMG + (size_t)h * HWDIM;
#define SB(v) ((v) >= 0.f ? 0x01u : 0xFFu)
#pragma unroll
  for (int it = 0; it < 4; ++it) {
    int idx = it * 256 + t;                // 0..1023
    int cib = idx >> 3;                    // ci block 0..127 (ci = cib*4)
    int w4 = (idx & 7) << 2;               // 0,4,...,28
    const float* p0 = xp + (size_t)(cib * 4 + 0) * PIX_PER_IMG + w4;
    float4 fa = *reinterpret_cast<const float4*>(p0);
    float4 fb = *reinterpret_cast<const float4*>(p0 + PIX_PER_IMG);
    float4 fc = *reinterpret_cast<const float4*>(p0 + 2 * PIX_PER_IMG);
    float4 fd = *reinterpret_cast<const float4*>(p0 + 3 * PIX_PER_IMG);
    unsigned o0 = SB(fa.x) | (SB(fb.x) << 8) | (SB(fc.x) << 16) | (SB(fd.x) << 24);
    unsigned o1 = SB(fa.y) | (SB(fb.y) << 8) | (SB(fc.y) << 16) | (SB(fd.y) << 24);
    unsigned o2 = SB(fa.z) | (SB(fb.z) << 8) | (SB(fc.z) << 16) | (SB(fd.z) << 24);
    unsigned o3 = SB(fa.w) | (SB(fb.w) << 8) | (SB(fc.w) << 16) | (SB(fd.w) << 24);
    tile[(w4 + 0) * 130 + cib] = (int)o0;
    tile[(w4 + 1) * 130 + cib] = (int)o1;
    tile[(w4 + 2) * 130 + cib] = (int)o2;
    tile[(w4 + 3) * 130 + cib] = (int)o3;
  }
  __syncthreads();
  int2* xo = reinterpret_cast<int2*>(xb + (size_t)plane * (HWDIM * CIN));
#pragma unroll
  for (int it = 0; it < 8; ++it) {
    int cc = it * 256 + t;                 // 8B chunk id 0..2047
    int w = cc >> 6, c8 = cc & 63;
    int2 v = make_int2(tile[w * 130 + c8 * 2], tile[w * 130 + c8 * 2 + 1]);
    xo[cc] = v;
  }
}

// ---------------- pack W: f32 OIHW -> int8 sign [tap][co][ci] ----------------
__global__ __launch_bounds__(256) void pack_w_kernel(const float* __restrict__ W,
                                                     signed char* __restrict__ wb) {
  int idx = blockIdx.x * 256 + threadIdx.x;     // 9*256*512 total
  int tap = idx / (COUT * CIN);
  int rem = idx - tap * (COUT * CIN);
  int co = rem >> 9;
  int ci = rem & 511;
  float v = W[((size_t)co * CIN + ci) * 9 + tap];
  wb[idx] = v >= 0.f ? 1 : -1;
}

// ---------------- conv: i8 MFMA GEMM, M=256 tile, 4-buffer ring, depth-2 prefetch ----
#define BM 256
#define BK 64
#define NSTEP 72
#define ABYTES (BM * BK)        // 16384
#define BUFB   (ABYTES + COUT * BK)  // 32768
#define LDS_TOTAL (4 * BUFB)    // 131072

__device__ __forceinline__ void load16(const void* g, void* l) {
  __builtin_amdgcn_global_load_lds((const __attribute__((address_space(1))) void*)g,
                                   (__attribute__((address_space(3))) void*)l, 16, 0, 0);
}

__global__ __launch_bounds__(512, 2) void conv_kernel(
    const signed char* __restrict__ xb,    // [2048][32][512]
    const signed char* __restrict__ wb,    // [9][256][512]
    short* __restrict__ cv,                // [64][256][1024]
    const signed char* __restrict__ zp,
    int* __restrict__ sum,
    unsigned long long* __restrict__ sumsq) {
  extern __shared__ signed char lds[];       // 128 KB, 4 ring buffers
  const int t = threadIdx.x;
  const int wid = t >> 6, lane = t & 63;
  const int b = blockIdx.x;                  // 0..255, one per CU
  const int nimg = b >> 2;
  const int h0 = (b & 3) * 8;                // 8 image rows per block

  const int wr = wid >> 2;                   // 0..1   (M dir, 128 rows each)
  const int wc = wid & 3;                    // 0..3   (N dir, 64 cols each)

  i32x4 acc[8][4];
#pragma unroll
  for (int m = 0; m < 8; ++m)
#pragma unroll
    for (int n = 0; n < 4; ++n) { i32x4 z = {0, 0, 0, 0}; acc[m][n] = z; }

  // stage: 4 x 16B loads/thread (2 A + 2 B), linear LDS dest, T2-swizzled source slot
  auto stage = [&](int buf, int step) {
    const int tap = step >> 3;
    const int s   = step & 7;
    const int ci0 = s << 6;
    const int dh = tap / 3 - 1, dw = tap % 3 - 1;
    signed char* dst = lds + buf * BUFB;
#pragma unroll
    for (int it = 0; it < 2; ++it) {
      int c = it * 512 + t;                  // A chunk 0..1023
      int r = c >> 2;                        // pixel row 0..255
      int soff = ((c & 3) ^ ((c >> 3) & 3)) << 4;
      int hs = h0 + (r >> 5) + dh;
      int ws = (r & 31) + dw;
      bool ok = ((unsigned)hs < 32u) && ((unsigned)ws < 32u);
      const signed char* src = ok
          ? xb + (((size_t)(nimg * 32 + hs) * 32 + ws) * CIN + ci0 + soff)
          : zp + soff;
      load16(src, (void*)(dst + c * 16));
    }
#pragma unroll
    for (int it = 0; it < 2; ++it) {
      int c = it * 512 + t;                  // B chunk 0..1023
      int co = c >> 2;
      int soff = ((c & 3) ^ ((c >> 3) & 3)) << 4;
      const signed char* src = wb + ((size_t)tap * COUT + co) * CIN + ci0 + soff;
      load16(src, (void*)(dst + ABYTES + c * 16));
    }
  };

  // read-side offsets (swizzle XOR uniform across m/n: depends on (lane&15)>>1)
  const int koff = (lane >> 4) << 4;
  const int ksw  = (((lane >> 1) & 3) << 4);
  int aoff[8], boff[4];
#pragma unroll
  for (int m = 0; m < 8; ++m) {
    int row = wr * 128 + m * 16 + (lane & 15);
    aoff[m] = row * BK + (koff ^ ksw);
  }
#pragma unroll
  for (int n = 0; n < 4; ++n) {
    int col = wc * 64 + n * 16 + (lane & 15);
    boff[n] = ABYTES + col * BK + (koff ^ ksw);
  }

  stage(0, 0);
  stage(1, 1);
  for (int step = 0; step < NSTEP; ++step) {
    if (step + 2 < NSTEP) {
      stage((step + 2) & 3, step + 2);
      asm volatile("s_waitcnt vmcnt(8)" ::: "memory");   // step's 4 loads done; 8 in flight
    } else if (step + 1 < NSTEP) {
      asm volatile("s_waitcnt vmcnt(4)" ::: "memory");
    } else {
      asm volatile("s_waitcnt vmcnt(0)" ::: "memory");
    }
    __builtin_amdgcn_s_barrier();            // single barrier per step (ring distance >= 2)
    const signed char* base = lds + (step & 3) * BUFB;
    i32x4 af[8], bf[4];
#pragma unroll
    for (int m = 0; m < 8; ++m)
      af[m] = *reinterpret_cast<const i32x4*>(base + aoff[m]);
#pragma unroll
    for (int n = 0; n < 4; ++n)
      bf[n] = *reinterpret_cast<const i32x4*>(base + boff[n]);
    __builtin_amdgcn_s_setprio(1);
#pragma unroll
    for (int m = 0; m < 8; ++m)
#pragma unroll
      for (int n = 0; n < 4; ++n)
        acc[m][n] = __builtin_amdgcn_mfma_i32_16x16x64_i8(af[m], bf[n], acc[m][n], 0, 0, 0);
    __builtin_amdgcn_s_setprio(0);
  }

  // epilogue A: write int16 conv output, NCHW
  const int P0 = b * BM;
#pragma unroll
  for (int m = 0; m < 8; ++m) {
#pragma unroll
    for (int n = 0; n < 4; ++n) {
      int row = wr * 128 + m * 16 + ((lane >> 4) << 2);
      int co = wc * 64 + n * 16 + (lane & 15);
      int P = P0 + row;
      int ni = P >> 10;
      int hw = P & 1023;
      short4 v = make_short4((short)acc[m][n][0], (short)acc[m][n][1],
                             (short)acc[m][n][2], (short)acc[m][n][3]);
      *reinterpret_cast<short4*>(cv + (((size_t)ni * COUT + co) << 10) + hw) = v;
    }
  }

  // epilogue B: fused per-channel sum / sumsq (exact integers)
#pragma unroll
  for (int n = 0; n < 4; ++n) {
    int s1 = 0;
    long long s2 = 0;
#pragma unroll
    for (int m = 0; m < 8; ++m)
#pragma unroll
      for (int j = 0; j < 4; ++j) {
        int v = acc[m][n][j];
        s1 += v;
        s2 += (long long)v * v;
      }
    s1 += __shfl_xor(s1, 16, 64);
    s1 += __shfl_xor(s1, 32, 64);
    s2 += __shfl_xor(s2, 16, 64);
    s2 += __shfl_xor(s2, 32, 64);
    if (lane < 16) {
      int c = wc * 64 + n * 16 + lane;
      atomicAdd(&sum[c], s1);
      atomicAdd(&sumsq[c], (unsigned long long)s2);
    }
  }
}

// ---------------- stats -> scale/shift ----------------
__global__ void stats_kernel(const int* __restrict__ sum,
                             const unsigned long long* __restrict__ sumsq,
                             const float* __restrict__ gamma,
                             const float* __restrict__ beta,
                             float* __restrict__ scale,
                             float* __restrict__ shift) {
  int co = threadIdx.x;
  double cnt = (double)NPIX;
  double mean = (double)sum[co] / cnt;
  double ex2 = (double)(long long)sumsq[co] / cnt;
  double var = ex2 - mean * mean;
  double rs = 1.0 / sqrt(var + 1e-5);
  float g = gamma[co];
  scale[co] = (float)rs * g;
  shift[co] = beta[co] - (float)(mean * rs) * g;
}

// ---------------- normalize + residual + clip (8 elems/thread) ----------------
__global__ __launch_bounds__(256) void final_kernel(const short* __restrict__ cv,
                                                    const float* __restrict__ x,
                                                    const float* __restrict__ scale,
                                                    const float* __restrict__ shift,
                                                    float* __restrict__ out) {
  size_t i = ((size_t)blockIdx.x * 256 + threadIdx.x) * 8;
  int co = (int)((i >> 10) & 255);
  size_t n = i >> 18;
  size_t hw = i & 1023;
  short4 c0 = *reinterpret_cast<const short4*>(cv + i);
  short4 c1 = *reinterpret_cast<const short4*>(cv + i + 4);
  const float* xr = x + ((n * CIN + co) << 10) + hw;
  float4 r0 = *reinterpret_cast<const float4*>(xr);
  float4 r1 = *reinterpret_cast<const float4*>(xr + 4);
  float sc = scale[co], sh = shift[co];
  float4 o0, o1;
  o0.x = fminf(1.f, fmaxf(-1.f, (float)c0.x * sc + sh + r0.x));
  o0.y = fminf(1.f, fmaxf(-1.f, (float)c0.y * sc + sh + r0.y));
  o0.z = fminf(1.f, fmaxf(-1.f, (float)c0.z * sc + sh + r0.z));
  o0.w = fminf(1.f, fmaxf(-1.f, (float)c0.w * sc + sh + r0.w));
  o1.x = fminf(1.f, fmaxf(-1.f, (float)c1.x * sc + sh + r1.x));
  o1.y = fminf(1.f, fmaxf(-1.f, (float)c1.y * sc + sh + r1.y));
  o1.z = fminf(1.f, fmaxf(-1.f, (float)c1.z * sc + sh + r1.z));
  o1.w = fminf(1.f, fmaxf(-1.f, (float)c1.w * sc + sh + r1.w));
  *reinterpret_cast<float4*>(out + i) = o0;
  *reinterpret_cast<float4*>(out + i + 4) = o1;
}

extern "C" void kernel_launch(void* const* d_in, const int* in_sizes, int n_in,
                              void* d_out, int out_size, void* d_ws, size_t ws_size,
                              hipStream_t stream) {
  const float* x     = (const float*)d_in[0];
  const float* W     = (const float*)d_in[1];
  const float* gamma = (const float*)d_in[2];
  const float* beta  = (const float*)d_in[3];
  float* out = (float*)d_out;
  char* ws = (char*)d_ws;

  signed char* xb = (signed char*)(ws + OFF_XB);
  signed char* wb = (signed char*)(ws + OFF_WB);
  short* cv = (short*)(ws + OFF_CONV);
  int* sum = (int*)(ws + OFF_STATS);
  unsigned long long* sumsq = (unsigned long long*)(ws + OFF_STATS + 1024);
  float* scale = (float*)(ws + OFF_SCALE);
  float* shift = (float*)(ws + OFF_SHIFT);
  signed char* zp = (signed char*)(ws + OFF_ZERO);

  // allow 128 KB dynamic LDS (host-side metadata; capture-safe, idempotent)
  hipFuncSetAttribute((const void*)conv_kernel,
                      hipFuncAttributeMaxDynamicSharedMemorySize, LDS_TOTAL);

  hipMemsetAsync(ws + OFF_STATS, 0, 5376, stream);

  pack_x_kernel<<<NBATCH * HWDIM, 256, 0, stream>>>(x, xb);
  pack_w_kernel<<<(9 * COUT * CIN) / 256, 256, 0, stream>>>(W, wb);
  conv_kernel<<<NPIX / BM, 512, LDS_TOTAL, stream>>>(xb, wb, cv, zp, sum, sumsq);
  stats_kernel<<<1, 256, 0, stream>>>(sum, sumsq, gamma, beta, scale, shift);
  final_kernel<<<(NBATCH * COUT * PIX_PER_IMG) / (256 * 8), 256, 0, stream>>>(
      cv, x, scale, shift, out);
}